// Round 5
// baseline (295.401 us; speedup 1.0000x reference)
//
#include <hip/hip_runtime.h>
#include <math.h>

#define SEQ 2048
#define DIM 1024

typedef __attribute__((ext_vector_type(8))) _Float16 half8;
typedef __attribute__((ext_vector_type(16))) float f32x16;

__device__ __forceinline__ unsigned short f2h(float f) {
    union { _Float16 h; unsigned short u; } c; c.h = (_Float16)f;
    return c.u;
}
__device__ __forceinline__ float gmask(int k) {
    float t = ((float)k - 1024.0f) * (1.0f / 512.0f);
    return expf(-0.5f * t * t);
}
__device__ __forceinline__ void glds16(const unsigned short* gp, unsigned short* lp) {
    __builtin_amdgcn_global_load_lds((const __attribute__((address_space(1))) void*)gp,
                                     (__attribute__((address_space(3))) void*)lp, 16, 0, 0);
}

// Stage a 128x64 fp16 tile (16 KB) from global (row stride ldK) into lds.
// Row r = 64 elems (8 slots of 16B); slot g^(r&7) holds global seg g
// -> fragment ds_read_b128 stays at the 8-access/bank structural minimum.
__device__ __forceinline__ void stage64(const unsigned short* __restrict__ g, int ldK,
                                        unsigned short* lds, int wave, int lane) {
    int row = wave * 32 + (lane >> 3);
    int seg = (lane & 7) ^ (lane >> 3);
    const unsigned short* gp = g + (long)row * ldK + seg * 8;
    unsigned short* lp = lds + wave * 2048;
    glds16(gp, lp);
    glds16(gp + 8 * (long)ldK, lp + 512);
    glds16(gp + 16 * (long)ldK, lp + 1024);
    glds16(gp + 24 * (long)ldK, lp + 1536);
}

enum { EPI_QKV = 0, EPI_EXP = 1, EPI_PV = 2, EPI_OUT = 3 };

// C = A @ B^T with 32x32x16 fp16 MFMA. A:[M,K], B:[N,K] fp16 row-major.
// EPI_QKV: N=3072 packed; writes Q, K, V^T [b][d][s] (+bias).
// EPI_EXP: writes fp16 exp(acc*scale*gmask(n)).
// EPI_PV : self-normalizing PV; row sums of A (expS) computed from LDS
//          during the K loop; writes fp16 acc/rowsum.
// EPI_OUT: writes fp32 acc + bias(n).
template <int EPI>
__global__ __launch_bounds__(256, 2) void mfma_gemm(
    const unsigned short* __restrict__ A, const unsigned short* __restrict__ Bm,
    const float* __restrict__ bias,
    float* __restrict__ Cf, unsigned short* __restrict__ Ch,
    int M, int N, int K, float scale, long sA, long sB, long sC)
{
    __shared__ unsigned short As[128 * 64];
    __shared__ unsigned short Bs[128 * 64];

    const int bz = blockIdx.z;
    const int tid = threadIdx.x;
    const int wave = tid >> 6;
    const int lane = tid & 63;
    const int wm = (wave & 1) * 64;
    const int wn = (wave >> 1) * 64;
    const long m0 = (long)blockIdx.y * 128;
    const long n0 = (long)blockIdx.x * 128;
    const int l31 = lane & 31;
    const int hk = lane >> 5;          // k-half for A/B operand layout

    const unsigned short* pA = A + bz * sA + m0 * K;
    const unsigned short* pB = Bm + bz * sB + n0 * K;

    f32x16 acc[2][2];
#pragma unroll
    for (int i = 0; i < 2; ++i)
#pragma unroll
        for (int j = 0; j < 2; ++j)
#pragma unroll
            for (int e = 0; e < 16; ++e) acc[i][j][e] = 0.f;

    // fragment LDS offsets (elems); operand layout: row = lane&31, k = 16t + hk*8 + j
    int aoff[2][4], boff[2][4];
#pragma unroll
    for (int i = 0; i < 2; ++i)
#pragma unroll
        for (int t = 0; t < 4; ++t) {
            int ar = wm + i * 32 + l31;
            aoff[i][t] = ar * 64 + (((2 * t + hk) ^ (ar & 7)) << 3);
            int br = wn + i * 32 + l31;
            boff[i][t] = br * 64 + (((2 * t + hk) ^ (br & 7)) << 3);
        }

    // PV row-sum accumulation assignment: this thread sums half the slots of one row
    const int pr = (wave & 1) * 64 + lane;   // local row 0..127
    const int ph = wave >> 1;                // slot parity half
    float psum = 0.f;

    for (int k0 = 0; k0 < K; k0 += 64) {
        stage64(pA + k0, K, As, wave, lane);
        stage64(pB + k0, K, Bs, wave, lane);
        __syncthreads();

        if (EPI == EPI_PV) {
            // sum this tile's 64 k-elems of row pr (slots split between ph=0/1,
            // XOR-phased so 64 lanes spread across all 8 slot-columns)
            const unsigned short* rowp = As + pr * 64;
#pragma unroll
            for (int i2 = 0; i2 < 4; ++i2) {
                half8 h = *(const half8*)(rowp + (((2 * i2 + ph) ^ (pr & 7)) << 3));
#pragma unroll
                for (int e = 0; e < 8; ++e) psum += (float)h[e];
            }
        }

#pragma unroll
        for (int t = 0; t < 4; ++t) {
            half8 a[2], b[2];
#pragma unroll
            for (int i = 0; i < 2; ++i) a[i] = *(const half8*)(As + aoff[i][t]);
#pragma unroll
            for (int j = 0; j < 2; ++j) b[j] = *(const half8*)(Bs + boff[j][t]);
#pragma unroll
            for (int i = 0; i < 2; ++i)
#pragma unroll
                for (int j = 0; j < 2; ++j)
                    acc[i][j] = __builtin_amdgcn_mfma_f32_32x32x16_f16(a[i], b[j], acc[i][j], 0, 0, 0);
        }
        __syncthreads();
    }

    // PV: publish partial row sums (As is dead after the last barrier)
    float* rsf = (float*)As;
    if (EPI == EPI_PV) {
        rsf[ph * 128 + pr] = psum;
        __syncthreads();
    }

    // ---- epilogue. C/D layout: col = lane&31, row = (e&3) + 8*(e>>2) + 4*hk
    const long MD = 8388608;  // 4*SEQ*DIM
    float* cF = (EPI == EPI_OUT) ? Cf + bz * sC : (float*)nullptr;
    unsigned short* cH = (EPI != EPI_OUT) ? Ch + bz * sC : (unsigned short*)nullptr;

    float bs_j[2], mult_j[2];
#pragma unroll
    for (int j = 0; j < 2; ++j) {
        int n = (int)n0 + wn + j * 32 + l31;
        if (EPI == EPI_QKV || EPI == EPI_OUT) bs_j[j] = bias[n];
        if (EPI == EPI_EXP) mult_j[j] = scale * gmask(n);
    }

#pragma unroll
    for (int i = 0; i < 2; ++i) {
#pragma unroll
        for (int q = 0; q < 4; ++q) {
            long mrow = m0 + wm + i * 32 + q * 8 + hk * 4;   // rows mrow..mrow+3
            int lr = wm + i * 32 + q * 8 + hk * 4;
            float inv4[4];
            if (EPI == EPI_PV) {
#pragma unroll
                for (int r = 0; r < 4; ++r)
                    inv4[r] = 1.0f / (rsf[lr + r] + rsf[128 + lr + r]);
            }
#pragma unroll
            for (int j = 0; j < 2; ++j) {
                int n = (int)n0 + wn + j * 32 + l31;
                if (EPI == EPI_QKV) {
                    int sel = n >> 10;   // block-uniform
                    int n1 = n & 1023;
                    float bs = bs_j[j];
                    if (sel < 2) {
                        unsigned short* dst = cH + (long)sel * MD;
#pragma unroll
                        for (int r = 0; r < 4; ++r)
                            dst[(mrow + r) * (long)DIM + n1] = f2h(acc[i][j][4 * q + r] + bs);
                    } else {
                        long b = mrow >> 11, s = mrow & 2047;
                        long idx = 2 * MD + b * (long)DIM * SEQ + (long)n1 * SEQ + s;
                        unsigned long long pk =
                            (unsigned long long)f2h(acc[i][j][4 * q + 0] + bs) |
                            ((unsigned long long)f2h(acc[i][j][4 * q + 1] + bs) << 16) |
                            ((unsigned long long)f2h(acc[i][j][4 * q + 2] + bs) << 32) |
                            ((unsigned long long)f2h(acc[i][j][4 * q + 3] + bs) << 48);
                        *(unsigned long long*)(cH + idx) = pk;
                    }
                } else if (EPI == EPI_EXP) {
#pragma unroll
                    for (int r = 0; r < 4; ++r)
                        cH[(mrow + r) * (long)N + n] = f2h(expf(acc[i][j][4 * q + r] * mult_j[j]));
                } else if (EPI == EPI_PV) {
#pragma unroll
                    for (int r = 0; r < 4; ++r)
                        cH[(mrow + r) * (long)N + n] = f2h(acc[i][j][4 * q + r] * inv4[r]);
                } else {  // EPI_OUT
#pragma unroll
                    for (int r = 0; r < 4; ++r)
                        cF[(mrow + r) * (long)N + n] = acc[i][j][4 * q + r] + bs_j[j];
                }
            }
        }
    }
}

// One-shot prep: x -> fp16, pack Wq|Wk|Wv|Wo -> fp16, pack bq|bk|bv -> fp32
__global__ __launch_bounds__(256) void prep(
    const float* __restrict__ x,
    const float* __restrict__ Wq, const float* __restrict__ Wk,
    const float* __restrict__ Wv, const float* __restrict__ Wo,
    const float* __restrict__ b0, const float* __restrict__ b1, const float* __restrict__ b2,
    unsigned short* __restrict__ xh, unsigned short* __restrict__ Wp, float* __restrict__ bqkv)
{
    long gid = (long)blockIdx.x * 256 + threadIdx.x;
    if (gid < 3072) {
        int sel = (int)(gid >> 10);
        const float* s = sel == 0 ? b0 : sel == 1 ? b1 : b2;
        bqkv[gid] = s[gid & 1023];
    }
    const long NX = 8388608 / 4;   // x float4 count
    const long NW = 1048576 / 4;   // per-weight float4 count (2^18)
    const long total = NX + 4 * NW;
    for (long i = gid; i < total; i += (long)gridDim.x * 256) {
        const float* src; unsigned short* dst; long off;
        if (i < NX) { src = x; dst = xh; off = i; }
        else {
            long wi = i - NX;
            int sel = (int)(wi >> 18);
            src = sel == 0 ? Wq : sel == 1 ? Wk : sel == 2 ? Wv : Wo;
            dst = Wp + ((long)sel << 20);
            off = wi & (NW - 1);
        }
        float4 v = ((const float4*)src)[off];
        unsigned long long p = (unsigned long long)f2h(v.x) | ((unsigned long long)f2h(v.y) << 16) |
                               ((unsigned long long)f2h(v.z) << 32) | ((unsigned long long)f2h(v.w) << 48);
        ((unsigned long long*)dst)[off] = p;
    }
}

extern "C" void kernel_launch(void* const* d_in, const int* in_sizes, int n_in,
                              void* d_out, int out_size, void* d_ws, size_t ws_size,
                              hipStream_t stream)
{
    const float* x  = (const float*)d_in[0];
    const float* Wq = (const float*)d_in[1];
    const float* bq = (const float*)d_in[2];
    const float* Wk = (const float*)d_in[3];
    const float* bk = (const float*)d_in[4];
    const float* Wv = (const float*)d_in[5];
    const float* bv = (const float*)d_in[6];
    const float* Wo = (const float*)d_in[7];
    const float* bo = (const float*)d_in[8];
    float* out = (float*)d_out;

    const long MD = 4L * SEQ * DIM;    // 8M
    const long WW = (long)DIM * DIM;   // 1M
    const long SD = (long)SEQ * DIM, SS = (long)SEQ * SEQ;

    unsigned short* xh   = (unsigned short*)d_ws;           // 16 MB
    unsigned short* Wp   = xh + MD;                         // 8 MB (Wqkv|Wo fp16)
    unsigned short* Woh  = Wp + 3 * WW;
    float* bqkv          = (float*)(Wp + 4 * WW);           // 3072 (+pad)
    unsigned short* Qh   = (unsigned short*)(bqkv + 4096);  // Q|K|VT contiguous 48 MB
    unsigned short* VT   = Qh + 2 * MD;                     // [B][D][S]
    unsigned short* expS = Qh + 3 * MD;                     // 33.5 MB
    unsigned short* O1   = xh;                              // alias: x dead after QKV

    dim3 blk(256);
    prep<<<4096, blk, 0, stream>>>(x, Wq, Wk, Wv, Wo, bq, bk, bv, xh, Wp, bqkv);

    // QKV fused: [8192,3072] = x @ Wqkv^T + bqkv -> Q, K, V^T
    mfma_gemm<EPI_QKV><<<dim3(3 * DIM / 128, (4 * SEQ) / 128, 1), blk, 0, stream>>>(
        xh, Wp, bqkv, nullptr, Qh, 4 * SEQ, 3 * DIM, DIM, 1.0f, 0, 0, 0);
    // scores -> expS = exp(QK^T/32 * gmask)
    mfma_gemm<EPI_EXP><<<dim3(SEQ / 128, SEQ / 128, 4), blk, 0, stream>>>(
        Qh, Qh + MD, nullptr, nullptr, expS, SEQ, SEQ, DIM, 0.03125f, SD, SD, SS);
    // O1 = (expS @ V) / rowsum(expS)   (row sums computed in-kernel)
    mfma_gemm<EPI_PV><<<dim3(DIM / 128, SEQ / 128, 4), blk, 0, stream>>>(
        expS, VT, nullptr, nullptr, O1, SEQ, DIM, SEQ, 1.0f, SS, (long)DIM * SEQ, SD);
    // out = O1 @ Wo^T + bo (fp32)
    mfma_gemm<EPI_OUT><<<dim3(DIM / 128, (4 * SEQ) / 128, 1), blk, 0, stream>>>(
        O1, Woh, bo, out, nullptr, 4 * SEQ, DIM, DIM, 1.0f, 0, 0, 0);
}

// Round 6
// 277.150 us; speedup vs baseline: 1.0659x; 1.0659x over previous
//
#include <hip/hip_runtime.h>
#include <math.h>

#define SEQ 2048
#define DIM 1024

typedef __attribute__((ext_vector_type(8))) _Float16 half8;
typedef __attribute__((ext_vector_type(4))) float f32x4;

__device__ __forceinline__ unsigned short f2h(float f) {
    union { _Float16 h; unsigned short u; } c; c.h = (_Float16)f;
    return c.u;
}
__device__ __forceinline__ float gmask(int k) {
    float t = ((float)k - 1024.0f) * (1.0f / 512.0f);
    return expf(-0.5f * t * t);
}
__device__ __forceinline__ void glds16(const unsigned short* gp, unsigned short* lp) {
    __builtin_amdgcn_global_load_lds((const __attribute__((address_space(1))) void*)gp,
                                     (__attribute__((address_space(3))) void*)lp, 16, 0, 0);
}

// Stage a 128x64 fp16 tile (16 KB) from global (row stride ldK) into lds.
// Row r = 64 elems (8 slots of 16B); LDS slot g^(r&7) holds global seg g.
// With the 16x16 fragment read pattern below this measured 0 bank conflicts
// (round 4); the 32x32 pattern (round 5) conflicted — do not switch back.
__device__ __forceinline__ void stage64(const unsigned short* __restrict__ g, int ldK,
                                        unsigned short* lds, int wave, int lane) {
    int row = wave * 32 + (lane >> 3);
    int seg = (lane & 7) ^ (lane >> 3);
    const unsigned short* gp = g + (long)row * ldK + seg * 8;
    unsigned short* lp = lds + wave * 2048;
    glds16(gp, lp);
    glds16(gp + 8 * (long)ldK, lp + 512);
    glds16(gp + 16 * (long)ldK, lp + 1024);
    glds16(gp + 24 * (long)ldK, lp + 1536);
}

enum { EPI_QKV = 0, EPI_EXP = 1, EPI_PV = 2, EPI_OUT = 3 };

// C = A @ B^T with 16x16x32 fp16 MFMA. A:[M,K], B:[N,K] fp16 row-major.
// EPI_QKV: N=3072 packed; writes Q, K, V^T [b][d][s] (+bias).
// EPI_EXP: writes fp16 exp(acc*scale*gmask(n)).
// EPI_PV : self-normalizing PV; row sums of A (expS) computed from LDS
//          during the K loop; writes fp16 acc/rowsum.
// EPI_OUT: writes fp32 acc + bias(n).
template <int EPI>
__global__ __launch_bounds__(256, 4) void mfma_gemm(
    const unsigned short* __restrict__ A, const unsigned short* __restrict__ Bm,
    const float* __restrict__ bias,
    float* __restrict__ Cf, unsigned short* __restrict__ Ch,
    int M, int N, int K, float scale, long sA, long sB, long sC)
{
    __shared__ unsigned short As[128 * 64];
    __shared__ unsigned short Bs[128 * 64];

    const int bz = blockIdx.z;
    const int tid = threadIdx.x;
    const int wave = tid >> 6;
    const int lane = tid & 63;
    const int wm = (wave & 1) * 64;
    const int wn = (wave >> 1) * 64;
    const long m0 = (long)blockIdx.y * 128;
    const long n0 = (long)blockIdx.x * 128;
    const int lm = lane & 15;
    const int lk = lane >> 4;

    const unsigned short* pA = A + bz * sA + m0 * K;
    const unsigned short* pB = Bm + bz * sB + n0 * K;

    f32x4 acc[4][4];
#pragma unroll
    for (int i = 0; i < 4; ++i)
#pragma unroll
        for (int j = 0; j < 4; ++j) {
            acc[i][j].x = 0.f; acc[i][j].y = 0.f; acc[i][j].z = 0.f; acc[i][j].w = 0.f;
        }

    // fragment LDS offsets (elems), swizzle applied: frag i, k-step t
    int aoff[4][2], boff[4][2];
#pragma unroll
    for (int i = 0; i < 4; ++i)
#pragma unroll
        for (int t = 0; t < 2; ++t) {
            int ar = wm + i * 16 + lm;
            aoff[i][t] = ar * 64 + (((4 * t + lk) ^ (ar & 7)) << 3);
            int br = wn + i * 16 + lm;
            boff[i][t] = br * 64 + (((4 * t + lk) ^ (br & 7)) << 3);
        }

    // PV row-sum assignment: thread sums half the slots of one local row
    const int pr = (wave & 1) * 64 + lane;   // local row 0..127 (x2 coverage)
    const int ph = wave >> 1;                // slot parity half
    float psum = 0.f;

    for (int k0 = 0; k0 < K; k0 += 64) {
        stage64(pA + k0, K, As, wave, lane);
        stage64(pB + k0, K, Bs, wave, lane);
        __syncthreads();

        if (EPI == EPI_PV) {
            const unsigned short* rowp = As + pr * 64;
#pragma unroll
            for (int i2 = 0; i2 < 4; ++i2) {
                half8 h = *(const half8*)(rowp + (((2 * i2 + ph) ^ (pr & 7)) << 3));
#pragma unroll
                for (int e = 0; e < 8; ++e) psum += (float)h[e];
            }
        }

#pragma unroll
        for (int t = 0; t < 2; ++t) {
            half8 a[4], b[4];
#pragma unroll
            for (int i = 0; i < 4; ++i) a[i] = *(const half8*)(As + aoff[i][t]);
#pragma unroll
            for (int j = 0; j < 4; ++j) b[j] = *(const half8*)(Bs + boff[j][t]);
#pragma unroll
            for (int i = 0; i < 4; ++i)
#pragma unroll
                for (int j = 0; j < 4; ++j)
                    acc[i][j] = __builtin_amdgcn_mfma_f32_16x16x32_f16(a[i], b[j], acc[i][j], 0, 0, 0);
        }
        __syncthreads();
    }

    // PV: publish partial row sums (As dead after last barrier)
    float* rsf = (float*)As;
    if (EPI == EPI_PV) {
        rsf[ph * 128 + pr] = psum;
        __syncthreads();
    }

    // ---- epilogue. C/D layout: col = lane&15, row = (lane>>4)*4 + r  [m89/m91]
    const long MD = 8388608;  // 4*SEQ*DIM
    float* cF = (EPI == EPI_OUT) ? Cf + bz * sC : (float*)nullptr;
    unsigned short* cH = (EPI != EPI_OUT) ? Ch + bz * sC : (unsigned short*)nullptr;

#pragma unroll
    for (int i = 0; i < 4; ++i) {
        long mrow = m0 + wm + i * 16 + lk * 4;   // rows mrow..mrow+3
        int lr = wm + i * 16 + lk * 4;
        float inv4[4];
        if (EPI == EPI_PV) {
#pragma unroll
            for (int r = 0; r < 4; ++r)
                inv4[r] = 1.0f / (rsf[lr + r] + rsf[128 + lr + r]);
        }
#pragma unroll
        for (int j = 0; j < 4; ++j) {
            int n = (int)n0 + wn + j * 16 + lm;
            if (EPI == EPI_QKV) {
                int sel = n >> 10;   // block-uniform (n0 multiple of 128)
                int n1 = n & 1023;
                float bs = bias[n];
                if (sel < 2) {
                    unsigned short* dst = cH + (long)sel * MD;
#pragma unroll
                    for (int r = 0; r < 4; ++r)
                        dst[(mrow + r) * (long)DIM + n1] = f2h(acc[i][j][r] + bs);
                } else {
                    long b = mrow >> 11, s = mrow & 2047;
                    long idx = 2 * MD + b * (long)DIM * SEQ + (long)n1 * SEQ + s;
                    unsigned long long pk =
                        (unsigned long long)f2h(acc[i][j].x + bs) |
                        ((unsigned long long)f2h(acc[i][j].y + bs) << 16) |
                        ((unsigned long long)f2h(acc[i][j].z + bs) << 32) |
                        ((unsigned long long)f2h(acc[i][j].w + bs) << 48);
                    *(unsigned long long*)(cH + idx) = pk;
                }
            } else if (EPI == EPI_EXP) {
                float mult = scale * gmask(n);
#pragma unroll
                for (int r = 0; r < 4; ++r)
                    cH[(mrow + r) * (long)N + n] = f2h(expf(acc[i][j][r] * mult));
            } else if (EPI == EPI_PV) {
#pragma unroll
                for (int r = 0; r < 4; ++r)
                    cH[(mrow + r) * (long)N + n] = f2h(acc[i][j][r] * inv4[r]);
            } else {  // EPI_OUT
                float bs = bias[n];
#pragma unroll
                for (int r = 0; r < 4; ++r)
                    cF[(mrow + r) * (long)N + n] = acc[i][j][r] + bs;
            }
        }
    }
}

// One-shot prep: x -> fp16, pack Wq|Wk|Wv|Wo -> fp16, pack bq|bk|bv -> fp32
__global__ __launch_bounds__(256) void prep(
    const float* __restrict__ x,
    const float* __restrict__ Wq, const float* __restrict__ Wk,
    const float* __restrict__ Wv, const float* __restrict__ Wo,
    const float* __restrict__ b0, const float* __restrict__ b1, const float* __restrict__ b2,
    unsigned short* __restrict__ xh, unsigned short* __restrict__ Wp, float* __restrict__ bqkv)
{
    long gid = (long)blockIdx.x * 256 + threadIdx.x;
    if (gid < 3072) {
        int sel = (int)(gid >> 10);
        const float* s = sel == 0 ? b0 : sel == 1 ? b1 : b2;
        bqkv[gid] = s[gid & 1023];
    }
    const long NX = 8388608 / 4;   // x float4 count
    const long NW = 1048576 / 4;   // per-weight float4 count (2^18)
    const long total = NX + 4 * NW;
    for (long i = gid; i < total; i += (long)gridDim.x * 256) {
        const float* src; unsigned short* dst; long off;
        if (i < NX) { src = x; dst = xh; off = i; }
        else {
            long wi = i - NX;
            int sel = (int)(wi >> 18);
            src = sel == 0 ? Wq : sel == 1 ? Wk : sel == 2 ? Wv : Wo;
            dst = Wp + ((long)sel << 20);
            off = wi & (NW - 1);
        }
        float4 v = ((const float4*)src)[off];
        unsigned long long p = (unsigned long long)f2h(v.x) | ((unsigned long long)f2h(v.y) << 16) |
                               ((unsigned long long)f2h(v.z) << 32) | ((unsigned long long)f2h(v.w) << 48);
        ((unsigned long long*)dst)[off] = p;
    }
}

extern "C" void kernel_launch(void* const* d_in, const int* in_sizes, int n_in,
                              void* d_out, int out_size, void* d_ws, size_t ws_size,
                              hipStream_t stream)
{
    const float* x  = (const float*)d_in[0];
    const float* Wq = (const float*)d_in[1];
    const float* bq = (const float*)d_in[2];
    const float* Wk = (const float*)d_in[3];
    const float* bk = (const float*)d_in[4];
    const float* Wv = (const float*)d_in[5];
    const float* bv = (const float*)d_in[6];
    const float* Wo = (const float*)d_in[7];
    const float* bo = (const float*)d_in[8];
    float* out = (float*)d_out;

    const long MD = 4L * SEQ * DIM;    // 8M
    const long WW = (long)DIM * DIM;   // 1M
    const long SD = (long)SEQ * DIM, SS = (long)SEQ * SEQ;

    unsigned short* xh   = (unsigned short*)d_ws;           // 16 MB
    unsigned short* Wp   = xh + MD;                         // 8 MB (Wqkv|Wo fp16)
    unsigned short* Woh  = Wp + 3 * WW;
    float* bqkv          = (float*)(Wp + 4 * WW);           // 3072 (+pad)
    unsigned short* Qh   = (unsigned short*)(bqkv + 4096);  // Q|K|VT contiguous 48 MB
    unsigned short* VT   = Qh + 2 * MD;                     // [B][D][S]
    unsigned short* expS = Qh + 3 * MD;                     // 33.5 MB
    unsigned short* O1   = xh;                              // alias: x dead after QKV

    dim3 blk(256);
    prep<<<4096, blk, 0, stream>>>(x, Wq, Wk, Wv, Wo, bq, bk, bv, xh, Wp, bqkv);

    // QKV fused: [8192,3072] = x @ Wqkv^T + bqkv -> Q, K, V^T
    mfma_gemm<EPI_QKV><<<dim3(3 * DIM / 128, (4 * SEQ) / 128, 1), blk, 0, stream>>>(
        xh, Wp, bqkv, nullptr, Qh, 4 * SEQ, 3 * DIM, DIM, 1.0f, 0, 0, 0);
    // scores -> expS = exp(QK^T/32 * gmask)
    mfma_gemm<EPI_EXP><<<dim3(SEQ / 128, SEQ / 128, 4), blk, 0, stream>>>(
        Qh, Qh + MD, nullptr, nullptr, expS, SEQ, SEQ, DIM, 0.03125f, SD, SD, SS);
    // O1 = (expS @ V) / rowsum(expS)   (row sums computed in-kernel)
    mfma_gemm<EPI_PV><<<dim3(DIM / 128, SEQ / 128, 4), blk, 0, stream>>>(
        expS, VT, nullptr, nullptr, O1, SEQ, DIM, SEQ, 1.0f, SS, (long)DIM * SEQ, SD);
    // out = O1 @ Wo^T + bo (fp32)
    mfma_gemm<EPI_OUT><<<dim3(DIM / 128, (4 * SEQ) / 128, 1), blk, 0, stream>>>(
        O1, Woh, bo, out, nullptr, 4 * SEQ, DIM, DIM, 1.0f, 0, 0, 0);
}